// Round 1
// baseline (3233.993 us; speedup 1.0000x reference)
//
#include <hip/hip_runtime.h>

#define DIMC   512
#define NHEADS 8
#define HDIM   64
#define DD     6
#define HHH    48
#define WWW    96
#define NPOS   (DD * HHH * WWW)   // 27648
#define KDD    3
#define KHH    5
#define KWW    5
#define NNB    (KDD * KHH * KWW)  // 75

// ---------------------------------------------------------------------------
// Tiled fp32 GEMM: C[M][N] = A[M][K] @ B[K][N] + bias[N]
// BM=BN=64, BK=16, 256 threads, 4x4 per-thread microtile.
// M % 64 == 0, N % 64 == 0, K % 16 == 0 guaranteed by the problem shapes.
// ---------------------------------------------------------------------------
__global__ __launch_bounds__(256) void gemm_bias_f32(
    const float* __restrict__ A, const float* __restrict__ B,
    const float* __restrict__ bias, float* __restrict__ C,
    int M, int N, int K)
{
    __shared__ float As[64][17];   // +1 pad: avoids 4-way bank conflict on broadcast reads
    __shared__ float Bs[16][64];

    const int tid = threadIdx.x;
    const int tx  = tid & 15;      // 0..15 -> N
    const int ty  = tid >> 4;      // 0..15 -> M
    const int m0  = blockIdx.y * 64;
    const int n0  = blockIdx.x * 64;

    // A tile load mapping: row = tid/4 (0..63), col-group = tid%4 (x4 floats)
    const int arow = tid >> 2;
    const int acg  = (tid & 3) * 4;
    // B tile load mapping: row = tid/16 (0..15), col-group = tid%16 (x4 floats)
    const int brow = tid >> 4;
    const int bcg  = (tid & 15) * 4;

    float acc[4][4];
#pragma unroll
    for (int i = 0; i < 4; i++)
#pragma unroll
        for (int j = 0; j < 4; j++) acc[i][j] = 0.0f;

    for (int k0 = 0; k0 < K; k0 += 16) {
        // stage A: 64x16
        float4 av = *reinterpret_cast<const float4*>(&A[(size_t)(m0 + arow) * K + k0 + acg]);
        As[arow][acg + 0] = av.x;
        As[arow][acg + 1] = av.y;
        As[arow][acg + 2] = av.z;
        As[arow][acg + 3] = av.w;
        // stage B: 16x64
        float4 bv = *reinterpret_cast<const float4*>(&B[(size_t)(k0 + brow) * N + n0 + bcg]);
        *reinterpret_cast<float4*>(&Bs[brow][bcg]) = bv;
        __syncthreads();

#pragma unroll
        for (int kk = 0; kk < 16; kk++) {
            float a[4], b[4];
#pragma unroll
            for (int i = 0; i < 4; i++) a[i] = As[ty * 4 + i][kk];
#pragma unroll
            for (int j = 0; j < 4; j++) b[j] = Bs[kk][tx * 4 + j];
#pragma unroll
            for (int i = 0; i < 4; i++)
#pragma unroll
                for (int j = 0; j < 4; j++) acc[i][j] += a[i] * b[j];
        }
        __syncthreads();
    }

    // epilogue: add bias, vector store
#pragma unroll
    for (int i = 0; i < 4; i++) {
        const int m = m0 + ty * 4 + i;
        const int n = n0 + tx * 4;
        float4 o;
        o.x = acc[i][0] + bias[n + 0];
        o.y = acc[i][1] + bias[n + 1];
        o.z = acc[i][2] + bias[n + 2];
        o.w = acc[i][3] + bias[n + 3];
        *reinterpret_cast<float4*>(&C[(size_t)m * N + n]) = o;
    }
}

// ---------------------------------------------------------------------------
// Neighborhood attention 3D, kernel (3,5,5).
// One block (512 threads = 8 waves) per spatial position; wave = head,
// lane = channel. qkv layout: [NPOS][1536] with q|k|v slabs of 512.
// q is scaled by 1/HDIM here (reference multiplies q by scale^2 = 1/64).
// ---------------------------------------------------------------------------
__global__ __launch_bounds__(512) void na3d_attn(
    const float* __restrict__ qkv, float* __restrict__ out)
{
    const int n    = blockIdx.x;          // position index
    const int head = threadIdx.x >> 6;    // 0..7
    const int lane = threadIdx.x & 63;    // 0..63 channel

    const int w = n % WWW;
    const int h = (n / WWW) % HHH;
    const int d = n / (WWW * HHH);

    const int sd = min(max(d - KDD / 2, 0), DD  - KDD);
    const int sh = min(max(h - KHH / 2, 0), HHH - KHH);
    const int sw = min(max(w - KWW / 2, 0), WWW - KWW);

    __shared__ float sc[NHEADS][NNB];

    const float qc = qkv[(size_t)n * 1536 + head * HDIM + lane] * (1.0f / 64.0f);

    // pass 1: scores
    int j = 0;
    for (int od = 0; od < KDD; od++)
        for (int oh = 0; oh < KHH; oh++)
#pragma unroll
            for (int ow = 0; ow < KWW; ow++, j++) {
                const int nb = ((sd + od) * HHH + (sh + oh)) * WWW + (sw + ow);
                const float kc = qkv[(size_t)nb * 1536 + 512 + head * HDIM + lane];
                float p = qc * kc;
#pragma unroll
                for (int o = 32; o > 0; o >>= 1) p += __shfl_xor(p, o);
                if (lane == 0) sc[head][j] = p;
            }
    __syncthreads();

    // softmax max
    float m = -1e30f;
#pragma unroll
    for (int t = 0; t < NNB; t++) m = fmaxf(m, sc[head][t]);

    // pass 2: exp-weighted V accumulation
    float sum = 0.0f;
    float acc = 0.0f;
    j = 0;
    for (int od = 0; od < KDD; od++)
        for (int oh = 0; oh < KHH; oh++)
#pragma unroll
            for (int ow = 0; ow < KWW; ow++, j++) {
                const int nb = ((sd + od) * HHH + (sh + oh)) * WWW + (sw + ow);
                const float e = __expf(sc[head][j] - m);
                sum += e;
                const float vc = qkv[(size_t)nb * 1536 + 1024 + head * HDIM + lane];
                acc += e * vc;
            }

    out[(size_t)n * DIMC + head * HDIM + lane] = acc / sum;
}

// ---------------------------------------------------------------------------
extern "C" void kernel_launch(void* const* d_in, const int* in_sizes, int n_in,
                              void* d_out, int out_size, void* d_ws, size_t ws_size,
                              hipStream_t stream)
{
    const float* x      = (const float*)d_in[0];
    const float* w_qkv  = (const float*)d_in[1];
    const float* b_qkv  = (const float*)d_in[2];
    const float* w_proj = (const float*)d_in[3];
    const float* b_proj = (const float*)d_in[4];
    float* out = (float*)d_out;

    float* qkv      = (float*)d_ws;                       // NPOS x 1536
    float* attn_out = qkv + (size_t)NPOS * 1536;          // NPOS x 512

    // 1) qkv = x @ w_qkv + b_qkv   (M=27648, K=512, N=1536)
    {
        dim3 grid(1536 / 64, NPOS / 64);
        gemm_bias_f32<<<grid, 256, 0, stream>>>(x, w_qkv, b_qkv, qkv, NPOS, 1536, DIMC);
    }
    // 2) neighborhood attention
    na3d_attn<<<NPOS, 512, 0, stream>>>(qkv, attn_out);
    // 3) out = attn_out @ w_proj + b_proj   (M=27648, K=512, N=512)
    {
        dim3 grid(512 / 64, NPOS / 64);
        gemm_bias_f32<<<grid, 256, 0, stream>>>(attn_out, w_proj, b_proj, out, NPOS, DIMC, DIMC);
    }
}

// Round 2
// 1185.133 us; speedup vs baseline: 2.7288x; 2.7288x over previous
//
#include <hip/hip_runtime.h>

#define DIMC   512
#define NHEADS 8
#define HDIM   64
#define DD     6
#define HHH    48
#define WWW    96
#define NPOS   (DD * HHH * WWW)   // 27648
#define KDD    3
#define KHH    5
#define KWW    5
#define NNB    (KDD * KHH * KWW)  // 75

// ---------------------------------------------------------------------------
// Tiled fp32 GEMM: C[M][N] = A[M][K] @ B[K][N] + bias[N]
// BM=BN=64, BK=16, 256 threads, 4x4 per-thread microtile.
// ---------------------------------------------------------------------------
__global__ __launch_bounds__(256) void gemm_bias_f32(
    const float* __restrict__ A, const float* __restrict__ B,
    const float* __restrict__ bias, float* __restrict__ C,
    int M, int N, int K)
{
    __shared__ float As[64][17];
    __shared__ float Bs[16][64];

    const int tid = threadIdx.x;
    const int tx  = tid & 15;
    const int ty  = tid >> 4;
    const int m0  = blockIdx.y * 64;
    const int n0  = blockIdx.x * 64;

    const int arow = tid >> 2;
    const int acg  = (tid & 3) * 4;
    const int brow = tid >> 4;
    const int bcg  = (tid & 15) * 4;

    float acc[4][4];
#pragma unroll
    for (int i = 0; i < 4; i++)
#pragma unroll
        for (int j = 0; j < 4; j++) acc[i][j] = 0.0f;

    for (int k0 = 0; k0 < K; k0 += 16) {
        float4 av = *reinterpret_cast<const float4*>(&A[(size_t)(m0 + arow) * K + k0 + acg]);
        As[arow][acg + 0] = av.x;
        As[arow][acg + 1] = av.y;
        As[arow][acg + 2] = av.z;
        As[arow][acg + 3] = av.w;
        float4 bv = *reinterpret_cast<const float4*>(&B[(size_t)(k0 + brow) * N + n0 + bcg]);
        *reinterpret_cast<float4*>(&Bs[brow][bcg]) = bv;
        __syncthreads();

#pragma unroll
        for (int kk = 0; kk < 16; kk++) {
            float a[4], b[4];
#pragma unroll
            for (int i = 0; i < 4; i++) a[i] = As[ty * 4 + i][kk];
#pragma unroll
            for (int j = 0; j < 4; j++) b[j] = Bs[kk][tx * 4 + j];
#pragma unroll
            for (int i = 0; i < 4; i++)
#pragma unroll
                for (int j = 0; j < 4; j++) acc[i][j] += a[i] * b[j];
        }
        __syncthreads();
    }

#pragma unroll
    for (int i = 0; i < 4; i++) {
        const int m = m0 + ty * 4 + i;
        const int n = n0 + tx * 4;
        float4 o;
        o.x = acc[i][0] + bias[n + 0];
        o.y = acc[i][1] + bias[n + 1];
        o.z = acc[i][2] + bias[n + 2];
        o.w = acc[i][3] + bias[n + 3];
        *reinterpret_cast<float4*>(&C[(size_t)m * N + n]) = o;
    }
}

// ---------------------------------------------------------------------------
// Neighborhood attention 3D, kernel (3,5,5) — single-pass online softmax.
// Block = 512 threads = 8 waves; wave = head. Within a wave:
//   group g = lane>>4 (4 neighbor-groups), i = lane&15 (channel quad, float4).
// One wave processes 4 neighbors per iteration: lane (g,i) loads K/V quad i of
// neighbor (4*it+g). Dot-product reduce = 4 shfl_xor steps within 16 lanes.
// Online (m, sum, acc) per group; flash-style combine across groups at end.
// Neighbor offsets precomputed once per block into LDS (table padded to 76).
// ---------------------------------------------------------------------------
__global__ __launch_bounds__(512) void na3d_attn(
    const float* __restrict__ qkv, float* __restrict__ out)
{
    const int n    = blockIdx.x;
    const int head = threadIdx.x >> 6;
    const int lane = threadIdx.x & 63;
    const int g    = lane >> 4;
    const int i    = lane & 15;

    __shared__ int nboff[76];

    if (threadIdx.x < 76) {
        const int w = n % WWW;
        const int h = (n / WWW) % HHH;
        const int d = n / (WWW * HHH);
        const int sd = min(max(d - KDD / 2, 0), DD  - KDD);
        const int sh = min(max(h - KHH / 2, 0), HHH - KHH);
        const int sw = min(max(w - KWW / 2, 0), WWW - KWW);
        const int j  = min((int)threadIdx.x, NNB - 1);
        const int od = j / 25, rem = j % 25;
        const int oh = rem / 5, ow = rem % 5;
        nboff[threadIdx.x] = (((sd + od) * HHH + (sh + oh)) * WWW + (sw + ow)) * 1536;
    }
    __syncthreads();

    const int coff = head * HDIM + i * 4;
    float4 q4 = *reinterpret_cast<const float4*>(qkv + (size_t)n * 1536 + coff);
    q4.x *= (1.0f / 64.0f); q4.y *= (1.0f / 64.0f);
    q4.z *= (1.0f / 64.0f); q4.w *= (1.0f / 64.0f);

    float m = -1e30f, ssum = 0.0f;
    float ax = 0.0f, ay = 0.0f, az = 0.0f, aw = 0.0f;

#pragma unroll
    for (int it = 0; it < 19; ++it) {
        const int j  = it * 4 + g;
        const int nb = nboff[j];
        const float4 k4 = *reinterpret_cast<const float4*>(qkv + nb + 512  + coff);
        const float4 v4 = *reinterpret_cast<const float4*>(qkv + nb + 1024 + coff);
        float s = q4.x * k4.x + q4.y * k4.y + q4.z * k4.z + q4.w * k4.w;
        s += __shfl_xor(s, 1);
        s += __shfl_xor(s, 2);
        s += __shfl_xor(s, 4);
        s += __shfl_xor(s, 8);
        if (j >= NNB) s = -1e30f;          // only last iteration can mask
        const float mnew  = fmaxf(m, s);
        const float scale = __expf(m - mnew);
        const float e     = __expf(s - mnew);
        ssum = ssum * scale + e;
        ax = ax * scale + e * v4.x;
        ay = ay * scale + e * v4.y;
        az = az * scale + e * v4.z;
        aw = aw * scale + e * v4.w;
        m = mnew;
    }

    // flash-style combine across the 4 neighbor-groups (xor 16, then 32)
#pragma unroll
    for (int off = 16; off <= 32; off <<= 1) {
        const float m2 = __shfl_xor(m, off);
        const float s2 = __shfl_xor(ssum, off);
        const float bx = __shfl_xor(ax, off);
        const float by = __shfl_xor(ay, off);
        const float bz = __shfl_xor(az, off);
        const float bw = __shfl_xor(aw, off);
        const float mx = fmaxf(m, m2);
        const float f1 = __expf(m - mx);
        const float f2 = __expf(m2 - mx);
        ssum = ssum * f1 + s2 * f2;
        ax = ax * f1 + bx * f2;
        ay = ay * f1 + by * f2;
        az = az * f1 + bz * f2;
        aw = aw * f1 + bw * f2;
        m = mx;
    }

    if (lane < 16) {
        const float inv = 1.0f / ssum;
        float4 o = { ax * inv, ay * inv, az * inv, aw * inv };
        *reinterpret_cast<float4*>(out + (size_t)n * DIMC + coff) = o;
    }
}

// ---------------------------------------------------------------------------
extern "C" void kernel_launch(void* const* d_in, const int* in_sizes, int n_in,
                              void* d_out, int out_size, void* d_ws, size_t ws_size,
                              hipStream_t stream)
{
    const float* x      = (const float*)d_in[0];
    const float* w_qkv  = (const float*)d_in[1];
    const float* b_qkv  = (const float*)d_in[2];
    const float* w_proj = (const float*)d_in[3];
    const float* b_proj = (const float*)d_in[4];
    float* out = (float*)d_out;

    float* qkv      = (float*)d_ws;              // NPOS x 1536
    float* attn_out = qkv + (size_t)NPOS * 1536; // NPOS x 512

    {
        dim3 grid(1536 / 64, NPOS / 64);
        gemm_bias_f32<<<grid, 256, 0, stream>>>(x, w_qkv, b_qkv, qkv, NPOS, 1536, DIMC);
    }
    na3d_attn<<<NPOS, 512, 0, stream>>>(qkv, attn_out);
    {
        dim3 grid(512 / 64, NPOS / 64);
        gemm_bias_f32<<<grid, 256, 0, stream>>>(attn_out, w_proj, b_proj, out, NPOS, DIMC, DIMC);
    }
}

// Round 3
// 489.333 us; speedup vs baseline: 6.6090x; 2.4219x over previous
//
#include <hip/hip_runtime.h>

#define DIMC   512
#define NHEADS 8
#define HDIM   64
#define DD     6
#define HHH    48
#define WWW    96
#define NPOS   (DD * HHH * WWW)   // 27648
#define KDD    3
#define KHH    5
#define KWW    5
#define NNB    (KDD * KHH * KWW)  // 75

typedef unsigned short u16;
typedef __attribute__((ext_vector_type(8))) short bf16x8;
typedef __attribute__((ext_vector_type(4))) float f32x4;

// bf16 <-> f32 helpers (RNE round)
static __device__ __forceinline__ float b2f(u16 u) {
    return __builtin_bit_cast(float, (unsigned)u << 16);
}
static __device__ __forceinline__ u16 f2b(float f) {
    unsigned x = __builtin_bit_cast(unsigned, f);
    return (u16)((x + 0x7fffu + ((x >> 16) & 1u)) >> 16);
}

static __device__ __forceinline__ void gload_lds16(const void* g, void* l) {
    __builtin_amdgcn_global_load_lds((const __attribute__((address_space(1))) void*)g,
                                     (__attribute__((address_space(3))) void*)l, 16, 0, 0);
}

// ---------------------------------------------------------------------------
// converts
// ---------------------------------------------------------------------------
__global__ __launch_bounds__(256) void cvt_x_bf16(const float* __restrict__ in,
                                                  u16* __restrict__ out, int n4) {
    const int i = blockIdx.x * 256 + threadIdx.x;  // exact grid
    float4 v = reinterpret_cast<const float4*>(in)[i];
    ushort4 o = { f2b(v.x), f2b(v.y), f2b(v.z), f2b(v.w) };
    reinterpret_cast<ushort4*>(out)[i] = o;
}

// w_qkv [512][1536] f32 -> w_qkvT [1536][512] bf16
__global__ __launch_bounds__(256) void cvt_wqkvT(const float* __restrict__ w,
                                                 u16* __restrict__ o) {
    const int id = blockIdx.x * 256 + threadIdx.x;   // 1536*512 exact
    const int nn = id >> 9, kk = id & 511;
    o[id] = f2b(w[(size_t)kk * 1536 + nn]);
}

// w_proj [512][512] f32 -> w_projT expanded [512 N][1536 K'] bf16: [Bh;Bh;Bl]
__global__ __launch_bounds__(256) void cvt_wprojT(const float* __restrict__ w,
                                                  u16* __restrict__ o) {
    const int id = blockIdx.x * 256 + threadIdx.x;   // 512*1536 exact
    const int nn = id / 1536, kp = id - nn * 1536;
    const int k = kp < 512 ? kp : (kp < 1024 ? kp - 512 : kp - 1024);
    const float v = w[(size_t)k * 512 + nn];
    const u16 h = f2b(v);
    o[id] = (kp < 1024) ? h : f2b(v - b2f(h));
}

// ---------------------------------------------------------------------------
// bf16 MFMA GEMM, m97 structure: 128x128 tile, BK=32, 256 thr = 4 waves (2x2),
// wave tile 64x64 = 4x4 frags of 16x16x32. A [M][lda] bf16 row-major with
// k-wrap (col = k<kwrap ? k : k-kwrap); B as B^T [N][ldb] bf16. Staging via
// global_load_lds width 16 (linear LDS, wave-uniform base + lane*16).
// ---------------------------------------------------------------------------
__global__ __launch_bounds__(256) void gemm_bf16_mfma(
    const u16* __restrict__ A, int lda, int kwrap,
    const u16* __restrict__ B, int ldb,
    const float* __restrict__ bias, int Kp,
    void* __restrict__ Cout, int ldc, int cmode)
{
    __shared__ u16 As[128 * 32];
    __shared__ u16 Bs[128 * 32];

    const int tid = threadIdx.x;
    const int l   = tid & 63;
    const int w   = tid >> 6;
    const int wr  = w >> 1, wc = w & 1;
    const int m0  = blockIdx.y * 128;
    const int n0  = blockIdx.x * 128;

    // staging map: chunk c = round*256 + tid -> row c>>2, col-elems (c&3)*8
    const int srow = tid >> 2;
    const int scol = (tid & 3) * 8;

    f32x4 acc[4][4];
#pragma unroll
    for (int i = 0; i < 4; i++)
#pragma unroll
        for (int j = 0; j < 4; j++) acc[i][j] = (f32x4)0.0f;

    const int lrow = l & 15;
    const int lk   = (l >> 4) * 8;

    for (int k0 = 0; k0 < Kp; k0 += 32) {
        const int ks = (k0 < kwrap) ? k0 : k0 - kwrap;
        const u16* ga = A + (size_t)(m0 + srow) * lda + ks + scol;
        const u16* gb = B + (size_t)(n0 + srow) * ldb + k0 + scol;
        // round 0: rows 0..63 ; round 1: rows 64..127
        gload_lds16(ga, As + w * 512);
        gload_lds16(ga + (size_t)64 * lda, As + 2048 + w * 512);
        gload_lds16(gb, Bs + w * 512);
        gload_lds16(gb + (size_t)64 * ldb, Bs + 2048 + w * 512);
        __syncthreads();

        bf16x8 af[4], bfr[4];
#pragma unroll
        for (int f = 0; f < 4; f++) {
            af[f]  = *reinterpret_cast<const bf16x8*>(&As[(wr * 64 + f * 16 + lrow) * 32 + lk]);
            bfr[f] = *reinterpret_cast<const bf16x8*>(&Bs[(wc * 64 + f * 16 + lrow) * 32 + lk]);
        }
#pragma unroll
        for (int i = 0; i < 4; i++)
#pragma unroll
            for (int j = 0; j < 4; j++)
                acc[i][j] = __builtin_amdgcn_mfma_f32_16x16x32_bf16(af[i], bfr[j], acc[i][j], 0, 0, 0);
        __syncthreads();
    }

    // epilogue: C[m][n], m = m0+wr*64+i*16+(l>>4)*4+r, n = n0+wc*64+j*16+(l&15)
#pragma unroll
    for (int i = 0; i < 4; i++) {
        const int mb = m0 + wr * 64 + i * 16 + (l >> 4) * 4;
#pragma unroll
        for (int j = 0; j < 4; j++) {
            const int n = n0 + wc * 64 + j * 16 + lrow;
            const float bv = bias[n];
#pragma unroll
            for (int r = 0; r < 4; r++) {
                const float v = acc[i][j][r] + bv;
                if (cmode) reinterpret_cast<u16*>(Cout)[(size_t)(mb + r) * ldc + n] = f2b(v);
                else       reinterpret_cast<float*>(Cout)[(size_t)(mb + r) * ldc + n] = v;
            }
        }
    }
}

// ---------------------------------------------------------------------------
// Neighborhood attention, bf16 in (qkv [NPOS][1536]), hi/lo bf16 out
// ([NPOS][1024]: cols 0-511 hi, 512-1023 lo). Same structure as R2.
// ---------------------------------------------------------------------------
__global__ __launch_bounds__(512) void na3d_attn(
    const u16* __restrict__ qkv, u16* __restrict__ outc)
{
    const int n    = blockIdx.x;
    const int head = threadIdx.x >> 6;
    const int lane = threadIdx.x & 63;
    const int g    = lane >> 4;
    const int i    = lane & 15;

    __shared__ int nboff[76];

    if (threadIdx.x < 76) {
        const int w = n % WWW;
        const int h = (n / WWW) % HHH;
        const int d = n / (WWW * HHH);
        const int sd = min(max(d - KDD / 2, 0), DD  - KDD);
        const int sh = min(max(h - KHH / 2, 0), HHH - KHH);
        const int sw = min(max(w - KWW / 2, 0), WWW - KWW);
        const int j  = min((int)threadIdx.x, NNB - 1);
        const int od = j / 25, rem = j % 25;
        const int oh = rem / 5, ow = rem % 5;
        nboff[threadIdx.x] = (((sd + od) * HHH + (sh + oh)) * WWW + (sw + ow)) * 1536;
    }
    __syncthreads();

    const int coff = head * HDIM + i * 4;
    const ushort4 qu = *reinterpret_cast<const ushort4*>(qkv + (size_t)n * 1536 + coff);
    const float qx = b2f(qu.x) * (1.0f / 64.0f);
    const float qy = b2f(qu.y) * (1.0f / 64.0f);
    const float qz = b2f(qu.z) * (1.0f / 64.0f);
    const float qw = b2f(qu.w) * (1.0f / 64.0f);

    float m = -1e30f, ssum = 0.0f;
    float ax = 0.0f, ay = 0.0f, az = 0.0f, aw = 0.0f;

#pragma unroll
    for (int it = 0; it < 19; ++it) {
        const int j  = it * 4 + g;
        const int nb = nboff[j];
        const ushort4 ku = *reinterpret_cast<const ushort4*>(qkv + nb + 512  + coff);
        const ushort4 vu = *reinterpret_cast<const ushort4*>(qkv + nb + 1024 + coff);
        float s = qx * b2f(ku.x) + qy * b2f(ku.y) + qz * b2f(ku.z) + qw * b2f(ku.w);
        s += __shfl_xor(s, 1);
        s += __shfl_xor(s, 2);
        s += __shfl_xor(s, 4);
        s += __shfl_xor(s, 8);
        if (j >= NNB) s = -1e30f;
        const float mnew  = fmaxf(m, s);
        const float scale = __expf(m - mnew);
        const float e     = __expf(s - mnew);
        ssum = ssum * scale + e;
        ax = ax * scale + e * b2f(vu.x);
        ay = ay * scale + e * b2f(vu.y);
        az = az * scale + e * b2f(vu.z);
        aw = aw * scale + e * b2f(vu.w);
        m = mnew;
    }

#pragma unroll
    for (int off = 16; off <= 32; off <<= 1) {
        const float m2 = __shfl_xor(m, off);
        const float s2 = __shfl_xor(ssum, off);
        const float bx = __shfl_xor(ax, off);
        const float by = __shfl_xor(ay, off);
        const float bz = __shfl_xor(az, off);
        const float bw = __shfl_xor(aw, off);
        const float mx = fmaxf(m, m2);
        const float f1 = __expf(m - mx);
        const float f2 = __expf(m2 - mx);
        ssum = ssum * f1 + s2 * f2;
        ax = ax * f1 + bx * f2;
        ay = ay * f1 + by * f2;
        az = az * f1 + bz * f2;
        aw = aw * f1 + bw * f2;
        m = mx;
    }

    if (lane < 16) {
        const float inv = 1.0f / ssum;
        const float ox = ax * inv, oy = ay * inv, oz = az * inv, ow = aw * inv;
        ushort4 hi, lo;
        hi.x = f2b(ox); lo.x = f2b(ox - b2f(hi.x));
        hi.y = f2b(oy); lo.y = f2b(oy - b2f(hi.y));
        hi.z = f2b(oz); lo.z = f2b(oz - b2f(hi.z));
        hi.w = f2b(ow); lo.w = f2b(ow - b2f(hi.w));
        *reinterpret_cast<ushort4*>(outc + (size_t)n * 1024 + coff)       = hi;
        *reinterpret_cast<ushort4*>(outc + (size_t)n * 1024 + 512 + coff) = lo;
    }
}

// ---------------------------------------------------------------------------
extern "C" void kernel_launch(void* const* d_in, const int* in_sizes, int n_in,
                              void* d_out, int out_size, void* d_ws, size_t ws_size,
                              hipStream_t stream)
{
    const float* x      = (const float*)d_in[0];
    const float* w_qkv  = (const float*)d_in[1];
    const float* b_qkv  = (const float*)d_in[2];
    const float* w_proj = (const float*)d_in[3];
    const float* b_proj = (const float*)d_in[4];
    float* out = (float*)d_out;

    // workspace layout (bf16 elements), all 16B aligned
    u16* qkvb   = (u16*)d_ws;                         // [27648][1536]
    u16* attnc  = qkvb  + (size_t)NPOS * 1536;        // [27648][1024] hi|lo
    u16* xb     = attnc + (size_t)NPOS * 1024;        // [27648][512]
    u16* wqkvT  = xb    + (size_t)NPOS * 512;         // [1536][512]
    u16* wprojT = wqkvT + (size_t)1536 * 512;         // [512][1536] expanded

    // converts
    cvt_x_bf16<<<(NPOS * 512 / 4) / 256, 256, 0, stream>>>(x, xb, NPOS * 512 / 4);
    cvt_wqkvT<<<(1536 * 512) / 256, 256, 0, stream>>>(w_qkv, wqkvT);
    cvt_wprojT<<<(512 * 1536) / 256, 256, 0, stream>>>(w_proj, wprojT);

    // 1) qkv = x @ w_qkv + b_qkv  (direct bf16, K=512), out bf16 [NPOS][1536]
    {
        dim3 grid(1536 / 128, NPOS / 128);
        gemm_bf16_mfma<<<grid, 256, 0, stream>>>(xb, 512, 1 << 30, wqkvT, 512,
                                                 b_qkv, 512, qkvb, 1536, 1);
    }
    // 2) attention -> hi/lo bf16 [NPOS][1024]
    na3d_attn<<<NPOS, 512, 0, stream>>>(qkvb, attnc);
    // 3) out = attn @ w_proj + b_proj  (3-term split as K'=1536, A wraps at 1024)
    {
        dim3 grid(512 / 128, NPOS / 128);
        gemm_bf16_mfma<<<grid, 256, 0, stream>>>(attnc, 1024, 1024, wprojT, 1536,
                                                 b_proj, 1536, out, 512, 0);
    }
}